// Round 7
// baseline (133.230 us; speedup 1.0000x reference)
//
#include <hip/hip_runtime.h>
#include <hip/hip_bf16.h>

// CapsuleLayer on MI355X — barrier-free K-loop, register-pipelined B.
// b stays 0 (faithful torch bug) => one dense conv 64ci->128co, 5x5, pad 2;
// v = squash_z1(p/(8*cnt)); out [N, t1, z1, H, W].
// K-loop: kw(5) x ks(2) outer [load 8 A row-frags from LDS, reused across kh],
// kh(5) inner [B frags from L2-hot Wr2, 2-step register prefetch pipeline],
// 800 MFMA fully unrolled, ZERO barriers after staging.

#define CO 128

typedef __attribute__((ext_vector_type(8))) short bf16x8;
typedef __attribute__((ext_vector_type(4))) float f32x4;

// ---- fused pre-pass:
// blocks 0..1023 : u [n][ci][h][w] fp32 -> ut [n][h][w][ci] bf16 (LDS transpose)
// blocks 1024..1123 : W fp32 [t0][co][z0][5][5] -> Wr2 bf16 [kk][co][ci]
__global__ __launch_bounds__(256) void k_pre(const float* __restrict__ u,
                                             const float* __restrict__ Wsrc,
                                             ushort* __restrict__ ut,
                                             ushort* __restrict__ Wr2) {
    int b = blockIdx.x;
    int t = threadIdx.x;
    if (b >= 1024) {
        int base = (b - 1024) * 2048 + t;
#pragma unroll
        for (int j = 0; j < 8; ++j) {
            int idx = base + j * 256;         // (kk*128+co)*64+ci
            int ci = idx & 63;
            int r  = idx >> 6;
            int co = r & 127;
            int kk = r >> 7;
            int t0 = ci >> 4, z0 = ci & 15;
            __hip_bfloat16 bb = __float2bfloat16(Wsrc[((t0 * CO + co) * 16 + z0) * 25 + kk]);
            Wr2[idx] = *(ushort*)&bb;
        }
        return;
    }
    __shared__ float lt[64][65];
    int wc = b & 1; int nh = b >> 1; int h = nh & 127; int n = nh >> 7;
    int w0 = wc * 64;
    int w = t & 63; int cg = t >> 6;
    const float* up = u + (size_t)n * (64 * 128 * 128) + h * 128 + w0 + w;
#pragma unroll
    for (int i = 0; i < 16; ++i) {
        int ci = cg * 16 + i;
        lt[w][ci] = up[(size_t)ci * (128 * 128)];
    }
    __syncthreads();
    int ci2 = t & 63; int pg = t >> 6;
    ushort* op = ut + (((size_t)(n * 128 + h)) * 128 + w0) * 64 + ci2;
#pragma unroll
    for (int i = 0; i < 16; ++i) {
        int w2 = pg * 16 + i;
        __hip_bfloat16 bv = __float2bfloat16(lt[w2][ci2]);
        op[(size_t)w2 * 64] = *(ushort*)&bv;
    }
}

// ---- main: grid 512 = 4(n) x 16(by: 8 rows) x 8(bx: 16 cols), 256 thr = 4 waves
// wave: wm4 = (wid>>1)*4 -> image rows [h0+wm4, +4); wn64 = (wid&1)*64 -> co.
// As stride 80 ushorts (160 B) — HW-verified conflict-free frag pattern (R4/R6).
__global__ __launch_bounds__(256, 2) void k_caps(const ushort* __restrict__ ut,
                                                 const ushort* __restrict__ Wr2,
                                                 float* __restrict__ out) {
    __shared__ ushort As[240 * 80];   // [p = rr*20+cc][ci pad] 38400 B

    int tid = threadIdx.x;
    int bid = blockIdx.x;
    int bx = bid & 7, by = (bid >> 3) & 15, n = bid >> 7;
    int h0 = by * 8, w0 = bx * 16;

    int lane = tid & 63, wid = tid >> 6;
    int wm4  = (wid >> 1) * 4;
    int wn64 = (wid & 1) * 64;
    int q = lane >> 4, m16 = lane & 15;

    // B pipeline base: Wr2[kk][co][ci], frag (kk,ks,ni) at
    //   bpb + kk*8192 + ni*1024 + ks*32
    const ushort* bpb = Wr2 + (wn64 + m16) * 64 + q * 8;

    // prime 2-deep pipeline: step s = kw*10+ks*5+kh; s=0 -> kk=0,ks=0;
    // s=1 -> kh=1 -> kk=5,ks=0
    bf16x8 bn1[4], bn2[4];
#pragma unroll
    for (int ni = 0; ni < 4; ++ni) {
        bn1[ni] = *(const bf16x8*)(bpb + ni * 1024);
        bn2[ni] = *(const bf16x8*)(bpb + 5 * 8192 + ni * 1024);
    }

    // stage A tile (pad-2 halo, zero OOB): 240 pixels x 8 chunks of 8 ci
    for (int i = tid; i < 1920; i += 256) {
        int p = i >> 3, c = i & 7;
        int rr = p / 20, cc = p - rr * 20;
        int hh = h0 + rr - 2, ww = w0 + cc - 2;
        bf16x8 v = {};
        if ((unsigned)hh < 128u && (unsigned)ww < 128u)
            v = *(const bf16x8*)(ut + (((size_t)(n * 128 + hh)) * 128 + ww) * 64 + c * 8);
        *(bf16x8*)&As[p * 80 + c * 8] = v;
    }
    __syncthreads();   // the ONLY barrier

    f32x4 acc[4][4] = {};
    int aBase = (wm4 * 20 + m16) * 80 + q * 8;

#pragma unroll
    for (int kw = 0; kw < 5; ++kw) {
#pragma unroll
        for (int ks = 0; ks < 2; ++ks) {
            // 8 A row-frags, reused across all 5 kh (rows wm4 .. wm4+7)
            bf16x8 a[8];
#pragma unroll
            for (int r = 0; r < 8; ++r)
                a[r] = *(const bf16x8*)&As[aBase + (r * 20 + kw) * 80 + ks * 32];
#pragma unroll
            for (int kh = 0; kh < 5; ++kh) {
                const int s = kw * 10 + ks * 5 + kh;
                bf16x8 bc[4];
#pragma unroll
                for (int ni = 0; ni < 4; ++ni) { bc[ni] = bn1[ni]; bn1[ni] = bn2[ni]; }
                const int s2 = s + 2;
                if (s2 < 50) {                         // prefetch step s+2
                    const int kw2 = s2 / 10, ks2 = (s2 / 5) & 1, kh2 = s2 % 5;
                    const int off2 = (kh2 * 5 + kw2) * 8192 + ks2 * 32;
#pragma unroll
                    for (int ni = 0; ni < 4; ++ni)
                        bn2[ni] = *(const bf16x8*)(bpb + off2 + ni * 1024);
                }
#pragma unroll
                for (int mi = 0; mi < 4; ++mi)
#pragma unroll
                    for (int ni = 0; ni < 4; ++ni)
                        acc[mi][ni] = __builtin_amdgcn_mfma_f32_16x16x32_bf16(
                            a[mi + kh], bc[ni], acc[mi][ni], 0, 0, 0);
            }
        }
    }

    // epilogue: scale 1/(8*cnt), squash over z1 (m16 lanes), store transposed
    // D layout: row(m = image col) = q*4+reg, col(n = co) = m16
#pragma unroll
    for (int mi = 0; mi < 4; ++mi) {
        int h = h0 + wm4 + mi;
        int hlo = h - 2; if (hlo < 0) hlo = 0;
        int hhi = h + 2; if (hhi > 127) hhi = 127;
        float cnth = (float)(hhi - hlo + 1);
#pragma unroll
        for (int ni = 0; ni < 4; ++ni) {
            f32x4 cv = acc[mi][ni];
            float ov[4];
#pragma unroll
            for (int reg = 0; reg < 4; ++reg) {
                int w = w0 + q * 4 + reg;
                int wlo = w - 2; if (wlo < 0) wlo = 0;
                int whi = w + 2; if (whi > 127) whi = 127;
                float s = 1.f / (8.f * cnth * (float)(whi - wlo + 1));
                float pv = cv[reg] * s;
                float n2 = pv * pv;
                n2 += __shfl_xor(n2, 1);
                n2 += __shfl_xor(n2, 2);
                n2 += __shfl_xor(n2, 4);
                n2 += __shfl_xor(n2, 8);
                float fac = n2 / ((1.f + n2) * sqrtf(n2 + 1e-9f));
                ov[reg] = pv * fac;
            }
            int co = wn64 + ni * 16 + m16;
            *(float4*)(out + (((size_t)(n * CO + co)) << 14) + h * 128 + w0 + q * 4) =
                make_float4(ov[0], ov[1], ov[2], ov[3]);
        }
    }
}

extern "C" void kernel_launch(void* const* d_in, const int* in_sizes, int n_in,
                              void* d_out, int out_size, void* d_ws, size_t ws_size,
                              hipStream_t stream) {
    const float* u    = (const float*)d_in[0];
    const float* Wsrc = (const float*)d_in[1];
    float* out = (float*)d_out;
    ushort* Wr2 = (ushort*)d_ws;                       // 409600 B
    ushort* ut  = (ushort*)((char*)d_ws + 409600);     // 8388608 B

    k_pre<<<1124, 256, 0, stream>>>(u, Wsrc, ut, Wr2);
    k_caps<<<512, 256, 0, stream>>>(ut, Wr2, out);
}

// Round 8
// 111.780 us; speedup vs baseline: 1.1919x; 1.1919x over previous
//
#include <hip/hip_runtime.h>
#include <hip/hip_bf16.h>

// CapsuleLayer on MI355X — R6 skeleton + per-(kw,ks) B staging + A kh-reuse.
// b stays 0 (faithful torch bug) => one dense conv 64ci->128co, 5x5, pad 2;
// v = squash_z1(p/(8*cnt)); out [N, t1, z1, H, W].
// K-loop: kw(5) x ks(2) outer [stage Bs = 5kh x 128co x 32ci from L2 with
// register prefetch; load 8 A row-frags reused across kh], kh(5) inner
// [4 B frags from LDS + 16 MFMA]. 20 barriers total, 2 blocks/CU (80 KB LDS).

#define CO 128

typedef __attribute__((ext_vector_type(8))) short bf16x8;
typedef __attribute__((ext_vector_type(4))) float f32x4;

// ---- fused pre-pass:
// blocks 0..1023   : u [n][ci][h][w] fp32 -> ut [n][h][w][ci] bf16
// blocks 1024..1123: W fp32 [t0][co][z0][5][5] -> Wr3 bf16 [kw][ks][kh][co][ci_l]
__global__ __launch_bounds__(256) void k_pre(const float* __restrict__ u,
                                             const float* __restrict__ Wsrc,
                                             ushort* __restrict__ ut,
                                             ushort* __restrict__ Wr3) {
    int b = blockIdx.x;
    int t = threadIdx.x;
    if (b >= 1024) {
        int base = (b - 1024) * 2048 + t;
#pragma unroll
        for (int j = 0; j < 8; ++j) {
            int idx = base + j * 256;          // ((((kw*2+ks)*5+kh)*128+co)*32+ci_l)
            int ci_l = idx & 31;
            int r    = idx >> 5;
            int co   = r & 127;
            int r2   = r >> 7;
            int kh   = r2 % 5;
            int kwks = r2 / 5;
            int ks = kwks & 1, kw = kwks >> 1;
            int ci = ks * 32 + ci_l;
            int t0 = ci >> 4, z0 = ci & 15;
            int kk = kh * 5 + kw;
            __hip_bfloat16 bb = __float2bfloat16(Wsrc[((t0 * CO + co) * 16 + z0) * 25 + kk]);
            Wr3[idx] = *(ushort*)&bb;
        }
        return;
    }
    __shared__ float lt[64][65];
    int wc = b & 1; int nh = b >> 1; int h = nh & 127; int n = nh >> 7;
    int w0 = wc * 64;
    int w = t & 63; int cg = t >> 6;
    const float* up = u + (size_t)n * (64 * 128 * 128) + h * 128 + w0 + w;
#pragma unroll
    for (int i = 0; i < 16; ++i) {
        int ci = cg * 16 + i;
        lt[w][ci] = up[(size_t)ci * (128 * 128)];
    }
    __syncthreads();
    int ci2 = t & 63; int pg = t >> 6;
    ushort* op = ut + (((size_t)(n * 128 + h)) * 128 + w0) * 64 + ci2;
#pragma unroll
    for (int i = 0; i < 16; ++i) {
        int w2 = pg * 16 + i;
        __hip_bfloat16 bv = __float2bfloat16(lt[w2][ci2]);
        op[(size_t)w2 * 64] = *(ushort*)&bv;
    }
}

// ---- main: grid 512 = 4(n) x 16(by: 8 rows) x 8(bx: 16 cols), 256 thr = 4 waves
// wave: wm4 = (wid>>1)*4 -> image rows [h0+wm4, +4); wn64 = (wid&1)*64 -> co.
// As stride 80 (HW-verified conflict-free). Bs stride 34 (fits 2 blk/CU).
__global__ __launch_bounds__(256, 2) void k_caps(const ushort* __restrict__ ut,
                                                 const ushort* __restrict__ Wr3,
                                                 float* __restrict__ out) {
    __shared__ ushort As[240 * 80];        // [p = rr*20+cc][ci pad80]  38400 B
    __shared__ ushort Bs[5 * 128 * 34];    // [kh][co][ci_l pad34]      43520 B

    int tid = threadIdx.x;
    int bid = blockIdx.x;
    int bx = bid & 7, by = (bid >> 3) & 15, n = bid >> 7;
    int h0 = by * 8, w0 = bx * 16;

    int lane = tid & 63, wid = tid >> 6;
    int wm4  = (wid >> 1) * 4;
    int wn64 = (wid & 1) * 64;
    int q = lane >> 4, m16 = lane & 15;

    // stage A tile (pad-2 halo, zero OOB): 240 pixels x 8 chunks of 8 ci
    for (int i = tid; i < 1920; i += 256) {
        int p = i >> 3, c = i & 7;
        int rr = p / 20, cc = p - rr * 20;
        int hh = h0 + rr - 2, ww = w0 + cc - 2;
        bf16x8 v = {};
        if ((unsigned)hh < 128u && (unsigned)ww < 128u)
            v = *(const bf16x8*)(ut + (((size_t)(n * 128 + hh)) * 128 + ww) * 64 + c * 8);
        *(bf16x8*)&As[p * 80 + c * 8] = v;
    }

    // register prefetch of B phase 0 (kw=0,ks=0): 10 chunks of 16 B per thread
    bf16x8 pre[10];
#pragma unroll
    for (int j = 0; j < 10; ++j)
        pre[j] = *(const bf16x8*)(Wr3 + (size_t)(tid + j * 256) * 8);

    f32x4 acc[4][4] = {};
    int aBase = (wm4 * 20 + m16) * 80 + q * 8;
    int bBase = (wn64 + m16) * 34 + q * 8;

#pragma unroll
    for (int kw = 0; kw < 5; ++kw) {
#pragma unroll
        for (int ks = 0; ks < 2; ++ks) {
            const int ph = kw * 2 + ks;
            __syncthreads();              // compute of previous phase done
#pragma unroll
            for (int j = 0; j < 10; ++j) {
                int c = tid + j * 256;    // chunk: kh = c>>9, co = (c&511)>>2, grp = c&3
                int kh_ = c >> 9, rem = c & 511;
                *(bf16x8*)&Bs[(kh_ * 128 + (rem >> 2)) * 34 + (rem & 3) * 8] = pre[j];
            }
            __syncthreads();
            if (ph < 9) {                 // prefetch next phase during compute
                const ushort* src = Wr3 + (size_t)(ph + 1) * 20480;
#pragma unroll
                for (int j = 0; j < 10; ++j)
                    pre[j] = *(const bf16x8*)(src + (size_t)(tid + j * 256) * 8);
            }
            // 8 A row-frags (rows wm4 .. wm4+7), reused across all 5 kh
            bf16x8 a[8];
#pragma unroll
            for (int r = 0; r < 8; ++r)
                a[r] = *(const bf16x8*)&As[aBase + (r * 20 + kw) * 80 + ks * 32];
#pragma unroll
            for (int kh = 0; kh < 5; ++kh) {
                bf16x8 bb[4];
#pragma unroll
                for (int ni = 0; ni < 4; ++ni)
                    bb[ni] = *(const bf16x8*)&Bs[kh * (128 * 34) + bBase + ni * (16 * 34)];
#pragma unroll
                for (int mi = 0; mi < 4; ++mi)
#pragma unroll
                    for (int ni = 0; ni < 4; ++ni)
                        acc[mi][ni] = __builtin_amdgcn_mfma_f32_16x16x32_bf16(
                            a[mi + kh], bb[ni], acc[mi][ni], 0, 0, 0);
            }
        }
    }

    // epilogue: scale 1/(8*cnt), squash over z1 (m16 lanes), store transposed
    // D layout: row(m = image col) = q*4+reg, col(n = co) = m16
#pragma unroll
    for (int mi = 0; mi < 4; ++mi) {
        int h = h0 + wm4 + mi;
        int hlo = h - 2; if (hlo < 0) hlo = 0;
        int hhi = h + 2; if (hhi > 127) hhi = 127;
        float cnth = (float)(hhi - hlo + 1);
#pragma unroll
        for (int ni = 0; ni < 4; ++ni) {
            f32x4 cv = acc[mi][ni];
            float ov[4];
#pragma unroll
            for (int reg = 0; reg < 4; ++reg) {
                int w = w0 + q * 4 + reg;
                int wlo = w - 2; if (wlo < 0) wlo = 0;
                int whi = w + 2; if (whi > 127) whi = 127;
                float s = 1.f / (8.f * cnth * (float)(whi - wlo + 1));
                float pv = cv[reg] * s;
                float n2 = pv * pv;
                n2 += __shfl_xor(n2, 1);
                n2 += __shfl_xor(n2, 2);
                n2 += __shfl_xor(n2, 4);
                n2 += __shfl_xor(n2, 8);
                float fac = n2 / ((1.f + n2) * sqrtf(n2 + 1e-9f));
                ov[reg] = pv * fac;
            }
            int co = wn64 + ni * 16 + m16;
            *(float4*)(out + (((size_t)(n * CO + co)) << 14) + h * 128 + w0 + q * 4) =
                make_float4(ov[0], ov[1], ov[2], ov[3]);
        }
    }
}

extern "C" void kernel_launch(void* const* d_in, const int* in_sizes, int n_in,
                              void* d_out, int out_size, void* d_ws, size_t ws_size,
                              hipStream_t stream) {
    const float* u    = (const float*)d_in[0];
    const float* Wsrc = (const float*)d_in[1];
    float* out = (float*)d_out;
    ushort* Wr3 = (ushort*)d_ws;                       // 409600 B
    ushort* ut  = (ushort*)((char*)d_ws + 409600);     // 8388608 B

    k_pre<<<1124, 256, 0, stream>>>(u, Wsrc, ut, Wr3);
    k_caps<<<512, 256, 0, stream>>>(ut, Wr3, out);
}